// Round 3
// baseline (450.017 us; speedup 1.0000x reference)
//
#include <hip/hip_runtime.h>
#include <math.h>

typedef __attribute__((ext_vector_type(8))) short short8;
typedef __attribute__((ext_vector_type(4))) float f32x4;
typedef unsigned short u16;

#define DEV static __device__ __forceinline__

DEV u16 f2bf(float f) {
  union { float f; unsigned u; } v; v.f = f;
  unsigned r = v.u + 0x7FFFu + ((v.u >> 16) & 1u);
  return (u16)(r >> 16);
}
DEV float bf2f(u16 u) {
  union { unsigned u; float f; } v; v.u = ((unsigned)u) << 16;
  return v.f;
}

// ---------------- K0: convert weights to bf16 ----------------
__global__ __launch_bounds__(256) void k_conv(const float* __restrict__ W,
                                              const float* __restrict__ Wf,
                                              u16* __restrict__ Wb,
                                              u16* __restrict__ Wfb) {
  int i = (blockIdx.x * 256 + threadIdx.x) * 4;
  const int NW = 1024 * 1024;
  if (i < NW) {
    float4 v = *(const float4*)(W + i);
    ushort4 o = {f2bf(v.x), f2bf(v.y), f2bf(v.z), f2bf(v.w)};
    *(ushort4*)(Wb + i) = o;
  } else {
    int j = i - NW;  // < 65536
    float4 v = *(const float4*)(Wf + j);
    ushort4 o = {f2bf(v.x), f2bf(v.y), f2bf(v.z), f2bf(v.w)};
    *(ushort4*)(Wfb + j) = o;
  }
}

// ---------------- K1: z = cos(x + a0[d]) * cos(a1[d]), bf16 ----------------
__global__ __launch_bounds__(256) void k_zenc(const float* __restrict__ x,
                                              const float* __restrict__ qp, // [64][3]
                                              u16* __restrict__ z) {
  __shared__ float a0[64], c1[64];
  int t = threadIdx.x;
  if (t < 64) { a0[t] = qp[t * 3]; c1[t] = cosf(qp[t * 3 + 1]); }
  __syncthreads();
  size_t i = ((size_t)blockIdx.x * 256 + t) * 4;
  float4 xv = *(const float4*)(x + i);
  int d = (int)(i & 63);
  ushort4 o;
  o.x = f2bf(cosf(xv.x + a0[d + 0]) * c1[d + 0]);
  o.y = f2bf(cosf(xv.y + a0[d + 1]) * c1[d + 1]);
  o.z = f2bf(cosf(xv.z + a0[d + 2]) * c1[d + 2]);
  o.w = f2bf(cosf(xv.w + a0[d + 3]) * c1[d + 3]);
  *(ushort4*)(z + i) = o;
}

// ---------- K2: fused  Y = Z @ W^T + x + b ;  X1 = LN1(Y) ; Q = enc(X1) ----
// BM=64 rows x BN=1024 (full row) per WG, BK=32, 8 waves (512 thr), 256 WGs.
// launch_bounds(512,2): 2 waves/EU -> 256-VGPR cap, no acc spill (round-2 bug).
// LDS tiles are XOR-swizzled (T2, both-sides rule #21): staging pre-swizzles
// the GLOBAL source column (LDS dest stays linear, as global_load_lds needs);
// reads apply the same involution. Granule swizzle: kb_phys = kb ^ ((row>>1)&3).
__global__ __launch_bounds__(512, 2) void k_gemm_ln1(
    const u16* __restrict__ Z, const u16* __restrict__ Wb,
    const float* __restrict__ x, const float* __restrict__ opb,
    const float* __restrict__ w1, const float* __restrict__ b1,
    const float* __restrict__ fqp,
    u16* __restrict__ X1, u16* __restrict__ Q) {
  constexpr int K = 1024;
  __shared__ __attribute__((aligned(16))) u16 As[2][64 * 32];     // 8 KB
  __shared__ __attribute__((aligned(16))) u16 Bs[2][1024 * 32];   // 128 KB
  __shared__ float redS[64][8];
  __shared__ float redQ[64][8];
  __shared__ float muF[64], rsF[64];

  int t = threadIdx.x, lane = t & 63, wv = t >> 6;
  int m0 = blockIdx.x * 64;

  // staging: thread t owns LDS granule (row = t>>2, kb_phys = t&3);
  // fetch logical granule kb_log = (t&3) ^ ((row>>1)&3) = (t&3) ^ ((t>>3)&3)
  int kb_log = (t & 3) ^ ((t >> 3) & 3);
  const u16* gA = Z + (size_t)(m0 + (t >> 2)) * K + kb_log * 8;
  const u16* gB = Wb + (size_t)(t >> 2) * K + kb_log * 8;

  auto stage = [&](int buf, int kt) {
    int ko = kt * 32;
    if (t < 256) {  // waves 0-3 stage A (64x32)
      __builtin_amdgcn_global_load_lds(
          (const __attribute__((address_space(1))) unsigned int*)(gA + ko),
          (__attribute__((address_space(3))) unsigned int*)&As[buf][wv * 512],
          16, 0, 0);
    }
#pragma unroll
    for (int j = 0; j < 8; ++j) {  // all 8 waves stage B (1024x32)
      __builtin_amdgcn_global_load_lds(
          (const __attribute__((address_space(1))) unsigned int*)(gB + (size_t)j * 128 * K + ko),
          (__attribute__((address_space(3))) unsigned int*)&Bs[buf][j * 4096 + wv * 512],
          16, 0, 0);
    }
  };

  f32x4 acc[4][8];
#pragma unroll
  for (int m = 0; m < 4; ++m)
#pragma unroll
    for (int n = 0; n < 8; ++n) acc[m][n] = (f32x4){0.f, 0.f, 0.f, 0.f};

  stage(0, 0);
  int cur = 0;
  int cl = lane & 15;
  // read-side swizzle: logical kb = lane>>4, row = *+cl, (row>>1)&3 = (lane>>1)&3
  int kofs = ((lane >> 4) ^ ((lane >> 1) & 3)) * 8;
  for (int kt = 0; kt < K / 32; ++kt) {
    __syncthreads();  // drains vmcnt -> buf[cur] landed; prev reads done
    if (kt + 1 < K / 32) stage(cur ^ 1, kt + 1);
    short8 av[4], bv[8];
#pragma unroll
    for (int m = 0; m < 4; ++m)
      av[m] = *(const short8*)&As[cur][(m * 16 + cl) * 32 + kofs];
#pragma unroll
    for (int n = 0; n < 8; ++n)
      bv[n] = *(const short8*)&Bs[cur][(wv * 128 + n * 16 + cl) * 32 + kofs];
#pragma unroll
    for (int m = 0; m < 4; ++m)
#pragma unroll
      for (int n = 0; n < 8; ++n)
        acc[m][n] = __builtin_amdgcn_mfma_f32_16x16x32_bf16(av[m], bv[n], acc[m][n], 0, 0, 0);
    cur ^= 1;
  }

  // ---- epilogue: residual + bias, LN1 stats, normalize, X1 + Q ----
  int rbase = (lane >> 4) * 4;  // C-frag row group (m89-verified layout)
  float w1c[8], b1c[8];
#pragma unroll
  for (int n = 0; n < 8; ++n) {
    int col = wv * 128 + n * 16 + cl;
    w1c[n] = w1[col];
    b1c[n] = b1[col];
  }
  float rowS[16], rowQ2[16];
#pragma unroll
  for (int i = 0; i < 16; ++i) { rowS[i] = 0.f; rowQ2[i] = 0.f; }
#pragma unroll
  for (int m = 0; m < 4; ++m) {
#pragma unroll
    for (int n = 0; n < 8; ++n) {
      int col = wv * 128 + n * 16 + cl;
      float bias = opb[col];
#pragma unroll
      for (int r = 0; r < 4; ++r) {
        int row = m * 16 + rbase + r;
        float v = acc[m][n][r] + x[(size_t)(m0 + row) * 1024 + col] + bias;
        acc[m][n][r] = v;
        rowS[m * 4 + r] += v;
        rowQ2[m * 4 + r] += v * v;
      }
    }
  }
#pragma unroll
  for (int i = 0; i < 16; ++i) {
#pragma unroll
    for (int msk = 1; msk < 16; msk <<= 1) {
      rowS[i] += __shfl_xor(rowS[i], msk, 64);
      rowQ2[i] += __shfl_xor(rowQ2[i], msk, 64);
    }
  }
  if (cl == 0) {
#pragma unroll
    for (int m = 0; m < 4; ++m)
#pragma unroll
      for (int r = 0; r < 4; ++r) {
        int row = m * 16 + rbase + r;
        redS[row][wv] = rowS[m * 4 + r];
        redQ[row][wv] = rowQ2[m * 4 + r];
      }
  }
  __syncthreads();
  if (t < 64) {
    float s = 0.f, q = 0.f;
#pragma unroll
    for (int w = 0; w < 8; ++w) { s += redS[t][w]; q += redQ[t][w]; }
    float mu = s * (1.f / 1024.f);
    float var = q * (1.f / 1024.f) - mu * mu;
    muF[t] = mu;
    rsF[t] = rsqrtf(var + 1e-5f);
  }
  __syncthreads();
#pragma unroll
  for (int m = 0; m < 4; ++m) {
#pragma unroll
    for (int r = 0; r < 4; ++r) {
      int row = m * 16 + rbase + r;
      float mu = muF[row], rs = rsF[row];
#pragma unroll
      for (int n = 0; n < 8; ++n) {
        int col = wv * 128 + n * 16 + cl;
        float x1 = (acc[m][n][r] - mu) * rs * w1c[n] + b1c[n];
        X1[(size_t)(m0 + row) * 1024 + col] = f2bf(x1);
        if (wv == 0 && n < 4) {  // cols 0-63: quantum FFN encoder input
          float qv = cosf(x1 + fqp[col * 3]) * cosf(fqp[col * 3 + 1]);
          Q[(size_t)(m0 + row) * 64 + col] = f2bf(qv);
        }
      }
    }
  }
}

// ---------------- K3: ffn = Q @ Wf^T; out = LN2(x1 + ffn + fb) ------------
__global__ __launch_bounds__(256) void k_ffn(const u16* __restrict__ X1,
                                             const u16* __restrict__ Q,
                                             const u16* __restrict__ Wfb,
                                             const float* __restrict__ fb,
                                             const float* __restrict__ w2,
                                             const float* __restrict__ b2,
                                             float* __restrict__ out) {
  __shared__ float t2[16][1024];  // 64 KB
  int t = threadIdx.x, lane = t & 63, wv = t >> 6;
  int m0 = blockIdx.x * 16;
  int kof = (lane >> 4) * 8;
  const short8 a0v = *(const short8*)&Q[(size_t)(m0 + (lane & 15)) * 64 + kof];
  const short8 a1v = *(const short8*)&Q[(size_t)(m0 + (lane & 15)) * 64 + 32 + kof];
  int nbase = wv * 256;
#pragma unroll
  for (int ni = 0; ni < 16; ++ni) {
    int n = nbase + ni * 16 + (lane & 15);
    short8 b0 = *(const short8*)&Wfb[(size_t)n * 64 + kof];
    short8 b1 = *(const short8*)&Wfb[(size_t)n * 64 + 32 + kof];
    f32x4 acc = (f32x4){0.f, 0.f, 0.f, 0.f};
    acc = __builtin_amdgcn_mfma_f32_16x16x32_bf16(a0v, b0, acc, 0, 0, 0);
    acc = __builtin_amdgcn_mfma_f32_16x16x32_bf16(a1v, b1, acc, 0, 0, 0);
#pragma unroll
    for (int r = 0; r < 4; ++r) t2[(lane >> 4) * 4 + r][n] = acc[r];
  }
  __syncthreads();
  for (int rr = 0; rr < 4; ++rr) {
    int row = wv * 4 + rr;
    size_t grow = (size_t)(m0 + row) * 1024;
    float vv[16];
    float s = 0.f, s2 = 0.f;
#pragma unroll
    for (int j = 0; j < 16; ++j) {
      int col = j * 64 + lane;
      float val = bf2f(X1[grow + col]) + t2[row][col] + fb[col];
      vv[j] = val; s += val; s2 += val * val;
    }
#pragma unroll
    for (int m = 1; m < 64; m <<= 1) { s += __shfl_xor(s, m, 64); s2 += __shfl_xor(s2, m, 64); }
    float mu = s * (1.f / 1024.f);
    float var = s2 * (1.f / 1024.f) - mu * mu;
    float rs = rsqrtf(var + 1e-5f);
#pragma unroll
    for (int j = 0; j < 16; ++j) {
      int col = j * 64 + lane;
      out[grow + col] = (vv[j] - mu) * rs * w2[col] + b2[col];
    }
  }
}

extern "C" void kernel_launch(void* const* d_in, const int* in_sizes, int n_in,
                              void* d_out, int out_size, void* d_ws, size_t ws_size,
                              hipStream_t stream) {
  const float* x   = (const float*)d_in[0];
  const float* aqp = (const float*)d_in[1];
  const float* opw = (const float*)d_in[2];
  const float* opb = (const float*)d_in[3];
  const float* fqp = (const float*)d_in[4];
  const float* flw = (const float*)d_in[5];
  const float* flb = (const float*)d_in[6];
  const float* n1w = (const float*)d_in[7];
  const float* n1b = (const float*)d_in[8];
  const float* n2w = (const float*)d_in[9];
  const float* n2b = (const float*)d_in[10];
  float* out = (float*)d_out;

  char* ws = (char*)d_ws;
  u16* zbuf = (u16*)(ws + 0);          // Z (bf16), becomes X1 in-place
  u16* Wb   = (u16*)(ws + 33554432);   // 1024x1024 bf16
  u16* Wfb  = (u16*)(ws + 35651584);   // 1024x64 bf16
  u16* Qb   = (u16*)(ws + 35782656);   // 16384x64 bf16

  k_conv<<<1088, 256, 0, stream>>>(opw, flw, Wb, Wfb);
  k_zenc<<<16384, 256, 0, stream>>>(x, aqp, zbuf);
  k_gemm_ln1<<<256, 512, 0, stream>>>(zbuf, Wb, x, opb, n1w, n1b, fqp,
                                      zbuf /*X1 in-place*/, Qb);
  k_ffn<<<1024, 256, 0, stream>>>(zbuf, Qb, Wfb, flb, n2w, n2b, out);
}

// Round 4
// 200.725 us; speedup vs baseline: 2.2420x; 2.2420x over previous
//
#include <hip/hip_runtime.h>
#include <math.h>

typedef __attribute__((ext_vector_type(8))) short short8;
typedef __attribute__((ext_vector_type(4))) float f32x4;
typedef unsigned short u16;

#define DEV static __device__ __forceinline__

DEV u16 f2bf(float f) {
  union { float f; unsigned u; } v; v.f = f;
  unsigned r = v.u + 0x7FFFu + ((v.u >> 16) & 1u);
  return (u16)(r >> 16);
}
DEV float bf2f(u16 u) {
  union { unsigned u; float f; } v; v.u = ((unsigned)u) << 16;
  return v.f;
}

// ---------------- K0: convert weights to bf16 ----------------
__global__ __launch_bounds__(256) void k_conv(const float* __restrict__ W,
                                              const float* __restrict__ Wf,
                                              u16* __restrict__ Wb,
                                              u16* __restrict__ Wfb) {
  int i = (blockIdx.x * 256 + threadIdx.x) * 4;
  const int NW = 1024 * 1024;
  if (i < NW) {
    float4 v = *(const float4*)(W + i);
    ushort4 o = {f2bf(v.x), f2bf(v.y), f2bf(v.z), f2bf(v.w)};
    *(ushort4*)(Wb + i) = o;
  } else {
    int j = i - NW;  // < 65536
    float4 v = *(const float4*)(Wf + j);
    ushort4 o = {f2bf(v.x), f2bf(v.y), f2bf(v.z), f2bf(v.w)};
    *(ushort4*)(Wfb + j) = o;
  }
}

// ---------------- K1: z = cos(x + a0[d]) * cos(a1[d]), bf16 ----------------
__global__ __launch_bounds__(256) void k_zenc(const float* __restrict__ x,
                                              const float* __restrict__ qp, // [64][3]
                                              u16* __restrict__ z) {
  __shared__ float a0[64], c1[64];
  int t = threadIdx.x;
  if (t < 64) { a0[t] = qp[t * 3]; c1[t] = cosf(qp[t * 3 + 1]); }
  __syncthreads();
  size_t i = ((size_t)blockIdx.x * 256 + t) * 4;
  float4 xv = *(const float4*)(x + i);
  int d = (int)(i & 63);
  ushort4 o;
  o.x = f2bf(cosf(xv.x + a0[d + 0]) * c1[d + 0]);
  o.y = f2bf(cosf(xv.y + a0[d + 1]) * c1[d + 1]);
  o.z = f2bf(cosf(xv.z + a0[d + 2]) * c1[d + 2]);
  o.w = f2bf(cosf(xv.w + a0[d + 3]) * c1[d + 3]);
  *(ushort4*)(z + i) = o;
}

// ---------- K2: Y = Z @ W^T + x + b (bf16 out) + per-slice LN1 stats ------
// Round-1 proven structure: 128x128 tile, BK=32, 4 waves, 64-float acc (no
// spill: VGPR 72 + 64 AGPR measured). Adds (a) round-3-verified both-sides
// granule swizzle (conflicts 3.3M -> 135K), (b) bf16 Y + stats epilogue.
__global__ __launch_bounds__(256) void k_gemm(const u16* __restrict__ Z,
                                              const u16* __restrict__ Wb,
                                              const float* __restrict__ x,
                                              const float* __restrict__ opb,
                                              u16* __restrict__ Ybf,
                                              float2* __restrict__ stats) {
  constexpr int K = 1024, N = 1024;
  __shared__ __attribute__((aligned(16))) u16 As[2][128 * 32];
  __shared__ __attribute__((aligned(16))) u16 Bs[2][128 * 32];
  int bid = blockIdx.x;
  int wg = (bid & 7) * 128 + (bid >> 3);  // XCD swizzle, 1024 % 8 == 0
  int mt = wg >> 3, nt = wg & 7;
  int m0 = mt * 128, n0 = nt * 128;
  int t = threadIdx.x, lane = t & 63, wv = t >> 6;
  int wr = wv >> 1, wc = wv & 1;

  // staging granule: row = t>>2, phys kb = t&3; fetch logical kb^((row>>1)&3)
  int kb_log = (t & 3) ^ ((t >> 3) & 3);
  const u16* gA = Z + (size_t)(m0 + (t >> 2)) * K + kb_log * 8;
  const u16* gB = Wb + (size_t)(n0 + (t >> 2)) * K + kb_log * 8;
  int lbase = wv * 512;

  f32x4 acc[4][4];
#pragma unroll
  for (int i = 0; i < 4; ++i)
#pragma unroll
    for (int j = 0; j < 4; ++j) acc[i][j] = (f32x4){0.f, 0.f, 0.f, 0.f};

  auto stage = [&](int buf, int kt) {
    const u16* ga = gA + kt * 32;
    const u16* gb = gB + kt * 32;
#pragma unroll
    for (int j = 0; j < 2; ++j) {
      __builtin_amdgcn_global_load_lds(
          (const __attribute__((address_space(1))) unsigned int*)(ga + (size_t)j * 64 * K),
          (__attribute__((address_space(3))) unsigned int*)&As[buf][j * 2048 + lbase],
          16, 0, 0);
      __builtin_amdgcn_global_load_lds(
          (const __attribute__((address_space(1))) unsigned int*)(gb + (size_t)j * 64 * K),
          (__attribute__((address_space(3))) unsigned int*)&Bs[buf][j * 2048 + lbase],
          16, 0, 0);
    }
  };

  stage(0, 0);
  int cl = lane & 15;
  // read-side swizzle: logical kb = lane>>4, row bits (1,2) come from cl
  int kofs = ((lane >> 4) ^ ((lane >> 1) & 3)) * 8;
  int arow = wr * 64 + cl;
  int brow = wc * 64 + cl;
  int cur = 0;
  for (int kt = 0; kt < K / 32; ++kt) {
    __syncthreads();
    if (kt + 1 < K / 32) stage(cur ^ 1, kt + 1);
    short8 av[4], bv[4];
#pragma unroll
    for (int mi = 0; mi < 4; ++mi)
      av[mi] = *(const short8*)&As[cur][(arow + mi * 16) * 32 + kofs];
#pragma unroll
    for (int ni = 0; ni < 4; ++ni)
      bv[ni] = *(const short8*)&Bs[cur][(brow + ni * 16) * 32 + kofs];
#pragma unroll
    for (int mi = 0; mi < 4; ++mi)
#pragma unroll
      for (int ni = 0; ni < 4; ++ni)
        acc[mi][ni] = __builtin_amdgcn_mfma_f32_16x16x32_bf16(av[mi], bv[ni], acc[mi][ni], 0, 0, 0);
    cur ^= 1;
  }

  // epilogue: v = acc + x + bias -> Ybf (bf16) + per-(row, 64col) stats
  int r0 = m0 + wr * 64 + (lane >> 4) * 4;
  int c0 = n0 + wc * 64 + cl;
  float rowS[16], rowQ2[16];
#pragma unroll
  for (int i = 0; i < 16; ++i) { rowS[i] = 0.f; rowQ2[i] = 0.f; }
#pragma unroll
  for (int mi = 0; mi < 4; ++mi) {
#pragma unroll
    for (int ni = 0; ni < 4; ++ni) {
      int col = c0 + ni * 16;
      float bcol = opb[col];
#pragma unroll
      for (int r = 0; r < 4; ++r) {
        size_t idx = (size_t)(r0 + mi * 16 + r) * N + col;
        float v = acc[mi][ni][r] + x[idx] + bcol;
        Ybf[idx] = f2bf(v);
        rowS[mi * 4 + r] += v;
        rowQ2[mi * 4 + r] += v * v;
      }
    }
  }
#pragma unroll
  for (int i = 0; i < 16; ++i) {
#pragma unroll
    for (int msk = 1; msk < 16; msk <<= 1) {
      rowS[i] += __shfl_xor(rowS[i], msk, 64);
      rowQ2[i] += __shfl_xor(rowQ2[i], msk, 64);
    }
  }
  if (cl == 0) {
#pragma unroll
    for (int mi = 0; mi < 4; ++mi)
#pragma unroll
      for (int r = 0; r < 4; ++r) {
        int rg = r0 + mi * 16 + r;
        stats[(size_t)rg * 16 + nt * 2 + wc] =
            make_float2(rowS[mi * 4 + r], rowQ2[mi * 4 + r]);
      }
  }
}

// ---------------- K3: X1 = LN1(Ybf) via stats; Q = enc(X1[:, :64]) --------
__global__ __launch_bounds__(256) void k_ln1(const u16* __restrict__ Ybf,
                                             const float2* __restrict__ stats,
                                             const float* __restrict__ w1,
                                             const float* __restrict__ b1,
                                             const float* __restrict__ fqp,
                                             u16* __restrict__ X1,
                                             u16* __restrict__ Q) {
  int t = threadIdx.x, lane = t & 63, wv = t >> 6;
  int row = blockIdx.x * 4 + wv;
  float2 st = stats[(size_t)row * 16 + (lane & 15)];
  float s = st.x, s2 = st.y;
#pragma unroll
  for (int msk = 1; msk < 16; msk <<= 1) {
    s += __shfl_xor(s, msk, 64);
    s2 += __shfl_xor(s2, msk, 64);
  }
  float mu = s * (1.f / 1024.f);
  float var = s2 * (1.f / 1024.f) - mu * mu;
  float rs = rsqrtf(var + 1e-5f);

  size_t base = (size_t)row * 1024 + lane * 16;
  short8 y0 = *(const short8*)&Ybf[base];
  short8 y1 = *(const short8*)&Ybf[base + 8];
  float x1v[16];
#pragma unroll
  for (int j = 0; j < 8; ++j) x1v[j] = bf2f((u16)y0[j]);
#pragma unroll
  for (int j = 0; j < 8; ++j) x1v[8 + j] = bf2f((u16)y1[j]);
  int col0 = lane * 16;
#pragma unroll
  for (int j = 0; j < 16; ++j)
    x1v[j] = (x1v[j] - mu) * rs * w1[col0 + j] + b1[col0 + j];
  short8 o0, o1;
#pragma unroll
  for (int j = 0; j < 8; ++j) { o0[j] = (short)f2bf(x1v[j]); o1[j] = (short)f2bf(x1v[8 + j]); }
  *(short8*)&X1[base] = o0;
  *(short8*)&X1[base + 8] = o1;

  if (lane < 4) {  // cols 0..63 feed the quantum FFN encoder
    short8 q0, q1;
#pragma unroll
    for (int j = 0; j < 16; ++j) {
      int c = col0 + j;
      float qv = cosf(x1v[j] + fqp[c * 3]) * cosf(fqp[c * 3 + 1]);
      if (j < 8) q0[j] = (short)f2bf(qv); else q1[j - 8] = (short)f2bf(qv);
    }
    *(short8*)&Q[(size_t)row * 64 + col0] = q0;
    *(short8*)&Q[(size_t)row * 64 + col0 + 8] = q1;
  }
}

// ---------------- K4: ffn = Q @ Wf^T; out = LN2(x1 + ffn + fb) ------------
__global__ __launch_bounds__(256) void k_ffn(const u16* __restrict__ X1,
                                             const u16* __restrict__ Q,
                                             const u16* __restrict__ Wfb,
                                             const float* __restrict__ fb,
                                             const float* __restrict__ w2,
                                             const float* __restrict__ b2,
                                             float* __restrict__ out) {
  __shared__ float t2[16][1024];  // 64 KB
  int t = threadIdx.x, lane = t & 63, wv = t >> 6;
  int m0 = blockIdx.x * 16;
  int kof = (lane >> 4) * 8;
  const short8 a0v = *(const short8*)&Q[(size_t)(m0 + (lane & 15)) * 64 + kof];
  const short8 a1v = *(const short8*)&Q[(size_t)(m0 + (lane & 15)) * 64 + 32 + kof];
  int nbase = wv * 256;
#pragma unroll
  for (int ni = 0; ni < 16; ++ni) {
    int n = nbase + ni * 16 + (lane & 15);
    short8 b0 = *(const short8*)&Wfb[(size_t)n * 64 + kof];
    short8 b1 = *(const short8*)&Wfb[(size_t)n * 64 + 32 + kof];
    f32x4 acc = (f32x4){0.f, 0.f, 0.f, 0.f};
    acc = __builtin_amdgcn_mfma_f32_16x16x32_bf16(a0v, b0, acc, 0, 0, 0);
    acc = __builtin_amdgcn_mfma_f32_16x16x32_bf16(a1v, b1, acc, 0, 0, 0);
#pragma unroll
    for (int r = 0; r < 4; ++r) t2[(lane >> 4) * 4 + r][n] = acc[r];
  }
  __syncthreads();
  for (int rr = 0; rr < 4; ++rr) {
    int row = wv * 4 + rr;
    size_t grow = (size_t)(m0 + row) * 1024;
    float vv[16];
    float s = 0.f, s2 = 0.f;
#pragma unroll
    for (int j = 0; j < 16; ++j) {
      int col = j * 64 + lane;
      float val = bf2f(X1[grow + col]) + t2[row][col] + fb[col];
      vv[j] = val; s += val; s2 += val * val;
    }
#pragma unroll
    for (int m = 1; m < 64; m <<= 1) { s += __shfl_xor(s, m, 64); s2 += __shfl_xor(s2, m, 64); }
    float mu = s * (1.f / 1024.f);
    float var = s2 * (1.f / 1024.f) - mu * mu;
    float rs = rsqrtf(var + 1e-5f);
#pragma unroll
    for (int j = 0; j < 16; ++j) {
      int col = j * 64 + lane;
      out[grow + col] = (vv[j] - mu) * rs * w2[col] + b2[col];
    }
  }
}

extern "C" void kernel_launch(void* const* d_in, const int* in_sizes, int n_in,
                              void* d_out, int out_size, void* d_ws, size_t ws_size,
                              hipStream_t stream) {
  const float* x   = (const float*)d_in[0];
  const float* aqp = (const float*)d_in[1];
  const float* opw = (const float*)d_in[2];
  const float* opb = (const float*)d_in[3];
  const float* fqp = (const float*)d_in[4];
  const float* flw = (const float*)d_in[5];
  const float* flb = (const float*)d_in[6];
  const float* n1w = (const float*)d_in[7];
  const float* n1b = (const float*)d_in[8];
  const float* n2w = (const float*)d_in[9];
  const float* n2b = (const float*)d_in[10];
  float* out = (float*)d_out;

  char* ws = (char*)d_ws;
  u16* zbuf = (u16*)(ws + 0);          // Z (bf16), becomes X1 (overwritten by k_ln1)
  u16* Wb   = (u16*)(ws + 33554432);   // 1024x1024 bf16
  u16* Wfb  = (u16*)(ws + 35651584);   // 1024x64 bf16
  u16* Qb   = (u16*)(ws + 35782656);   // 16384x64 bf16

  // d_out doubles as pre-FFN scratch: bf16 Y in [0, 32MB), LN1 stats in
  // [32MB, 34MB). k_ffn fully overwrites d_out with the final fp32 result.
  u16* Ybf = (u16*)d_out;
  float2* stats = (float2*)((char*)d_out + 33554432);

  k_conv<<<1088, 256, 0, stream>>>(opw, flw, Wb, Wfb);
  k_zenc<<<16384, 256, 0, stream>>>(x, aqp, zbuf);
  k_gemm<<<1024, 256, 0, stream>>>(zbuf, Wb, x, opb, Ybf, stats);
  k_ln1<<<4096, 256, 0, stream>>>(Ybf, stats, n1w, n1b, fqp, zbuf /*X1*/, Qb);
  k_ffn<<<1024, 256, 0, stream>>>(zbuf, Qb, Wfb, flb, n2w, n2b, out);
}

// Round 5
// 155.564 us; speedup vs baseline: 2.8928x; 1.2903x over previous
//
#include <hip/hip_runtime.h>
#include <math.h>

typedef __attribute__((ext_vector_type(8))) short short8;
typedef __attribute__((ext_vector_type(4))) float f32x4;
typedef unsigned short u16;

#define DEV static __device__ __forceinline__

DEV u16 f2bf(float f) {
  union { float f; unsigned u; } v; v.f = f;
  unsigned r = v.u + 0x7FFFu + ((v.u >> 16) & 1u);
  return (u16)(r >> 16);
}
DEV float bf2f(u16 u) {
  union { unsigned u; float f; } v; v.u = ((unsigned)u) << 16;
  return v.f;
}

// ---------------- K0: convert weights to bf16 ----------------
__global__ __launch_bounds__(256) void k_conv(const float* __restrict__ W,
                                              const float* __restrict__ Wf,
                                              u16* __restrict__ Wb,
                                              u16* __restrict__ Wfb) {
  int i = (blockIdx.x * 256 + threadIdx.x) * 4;
  const int NW = 1024 * 1024;
  if (i < NW) {
    float4 v = *(const float4*)(W + i);
    ushort4 o = {f2bf(v.x), f2bf(v.y), f2bf(v.z), f2bf(v.w)};
    *(ushort4*)(Wb + i) = o;
  } else {
    int j = i - NW;  // < 65536
    float4 v = *(const float4*)(Wf + j);
    ushort4 o = {f2bf(v.x), f2bf(v.y), f2bf(v.z), f2bf(v.w)};
    *(ushort4*)(Wfb + j) = o;
  }
}

// ---------------- K1: z = cos(x + a0[d]) * cos(a1[d]), bf16 ----------------
__global__ __launch_bounds__(256) void k_zenc(const float* __restrict__ x,
                                              const float* __restrict__ qp, // [64][3]
                                              u16* __restrict__ z) {
  __shared__ float a0[64], c1[64];
  int t = threadIdx.x;
  if (t < 64) { a0[t] = qp[t * 3]; c1[t] = cosf(qp[t * 3 + 1]); }
  __syncthreads();
  size_t i = ((size_t)blockIdx.x * 256 + t) * 4;
  float4 xv = *(const float4*)(x + i);
  int d = (int)(i & 63);
  ushort4 o;
  o.x = f2bf(cosf(xv.x + a0[d + 0]) * c1[d + 0]);
  o.y = f2bf(cosf(xv.y + a0[d + 1]) * c1[d + 1]);
  o.z = f2bf(cosf(xv.z + a0[d + 2]) * c1[d + 2]);
  o.w = f2bf(cosf(xv.w + a0[d + 3]) * c1[d + 3]);
  *(ushort4*)(z + i) = o;
}

// ---------- K2: Y = Z @ W^T + x + b  -> bf16 Y (minimal epilogue) ---------
// Round-1 proven structure: 128x128 tile, BK=32, 4 waves (VGPR 72, occ 22%).
// + both-sides granule swizzle (round-4 verified: conflicts 4.2M -> 0).
// Epilogue kept minimal on purpose: round-4's in-kernel LN stats pushed VGPR
// to 136 (> the 128 occupancy step) and halved occupancy -> 127us. Stats are
// recomputed from bf16 Y in k_ln1 instead (error << threshold).
__global__ __launch_bounds__(256) void k_gemm(const u16* __restrict__ Z,
                                              const u16* __restrict__ Wb,
                                              const float* __restrict__ x,
                                              const float* __restrict__ opb,
                                              u16* __restrict__ Ybf) {
  constexpr int K = 1024, N = 1024;
  __shared__ __attribute__((aligned(16))) u16 As[2][128 * 32];
  __shared__ __attribute__((aligned(16))) u16 Bs[2][128 * 32];
  int bid = blockIdx.x;
  int wg = (bid & 7) * 128 + (bid >> 3);  // XCD swizzle, 1024 % 8 == 0
  int mt = wg >> 3, nt = wg & 7;
  int m0 = mt * 128, n0 = nt * 128;
  int t = threadIdx.x, lane = t & 63, wv = t >> 6;
  int wr = wv >> 1, wc = wv & 1;

  // staging granule: row = t>>2, phys kb = t&3; fetch logical kb^((row>>1)&3)
  int kb_log = (t & 3) ^ ((t >> 3) & 3);
  const u16* gA = Z + (size_t)(m0 + (t >> 2)) * K + kb_log * 8;
  const u16* gB = Wb + (size_t)(n0 + (t >> 2)) * K + kb_log * 8;
  int lbase = wv * 512;

  f32x4 acc[4][4];
#pragma unroll
  for (int i = 0; i < 4; ++i)
#pragma unroll
    for (int j = 0; j < 4; ++j) acc[i][j] = (f32x4){0.f, 0.f, 0.f, 0.f};

  auto stage = [&](int buf, int kt) {
    const u16* ga = gA + kt * 32;
    const u16* gb = gB + kt * 32;
#pragma unroll
    for (int j = 0; j < 2; ++j) {
      __builtin_amdgcn_global_load_lds(
          (const __attribute__((address_space(1))) unsigned int*)(ga + (size_t)j * 64 * K),
          (__attribute__((address_space(3))) unsigned int*)&As[buf][j * 2048 + lbase],
          16, 0, 0);
      __builtin_amdgcn_global_load_lds(
          (const __attribute__((address_space(1))) unsigned int*)(gb + (size_t)j * 64 * K),
          (__attribute__((address_space(3))) unsigned int*)&Bs[buf][j * 2048 + lbase],
          16, 0, 0);
    }
  };

  stage(0, 0);
  int cl = lane & 15;
  // read-side swizzle: logical kb = lane>>4, row bits (1,2) come from cl
  int kofs = ((lane >> 4) ^ ((lane >> 1) & 3)) * 8;
  int arow = wr * 64 + cl;
  int brow = wc * 64 + cl;
  int cur = 0;
  for (int kt = 0; kt < K / 32; ++kt) {
    __syncthreads();
    if (kt + 1 < K / 32) stage(cur ^ 1, kt + 1);
    short8 av[4], bv[4];
#pragma unroll
    for (int mi = 0; mi < 4; ++mi)
      av[mi] = *(const short8*)&As[cur][(arow + mi * 16) * 32 + kofs];
#pragma unroll
    for (int ni = 0; ni < 4; ++ni)
      bv[ni] = *(const short8*)&Bs[cur][(brow + ni * 16) * 32 + kofs];
#pragma unroll
    for (int mi = 0; mi < 4; ++mi)
#pragma unroll
      for (int ni = 0; ni < 4; ++ni)
        acc[mi][ni] = __builtin_amdgcn_mfma_f32_16x16x32_bf16(av[mi], bv[ni], acc[mi][ni], 0, 0, 0);
    cur ^= 1;
  }

  // minimal epilogue: v = acc + x + bias -> bf16 store
  int r0 = m0 + wr * 64 + (lane >> 4) * 4;
  int c0 = n0 + wc * 64 + cl;
#pragma unroll
  for (int mi = 0; mi < 4; ++mi) {
#pragma unroll
    for (int ni = 0; ni < 4; ++ni) {
      int col = c0 + ni * 16;
      float bcol = opb[col];
#pragma unroll
      for (int r = 0; r < 4; ++r) {
        size_t idx = (size_t)(r0 + mi * 16 + r) * N + col;
        Ybf[idx] = f2bf(acc[mi][ni][r] + x[idx] + bcol);
      }
    }
  }
}

// ---------------- K3: X1 = LN1(Ybf); Q = enc(X1[:, :64]) ------------------
// One wave per row; stats computed from the bf16 Y row itself.
__global__ __launch_bounds__(256) void k_ln1(const u16* __restrict__ Ybf,
                                             const float* __restrict__ w1,
                                             const float* __restrict__ b1,
                                             const float* __restrict__ fqp,
                                             u16* __restrict__ X1,
                                             u16* __restrict__ Q) {
  int t = threadIdx.x, lane = t & 63, wv = t >> 6;
  int row = blockIdx.x * 4 + wv;
  size_t base = (size_t)row * 1024 + lane * 16;
  short8 y0 = *(const short8*)&Ybf[base];
  short8 y1 = *(const short8*)&Ybf[base + 8];
  float yv[16];
#pragma unroll
  for (int j = 0; j < 8; ++j) yv[j] = bf2f((u16)y0[j]);
#pragma unroll
  for (int j = 0; j < 8; ++j) yv[8 + j] = bf2f((u16)y1[j]);
  float s = 0.f, s2 = 0.f;
#pragma unroll
  for (int j = 0; j < 16; ++j) { s += yv[j]; s2 += yv[j] * yv[j]; }
#pragma unroll
  for (int msk = 1; msk < 64; msk <<= 1) {
    s += __shfl_xor(s, msk, 64);
    s2 += __shfl_xor(s2, msk, 64);
  }
  float mu = s * (1.f / 1024.f);
  float var = s2 * (1.f / 1024.f) - mu * mu;
  float rs = rsqrtf(var + 1e-5f);

  int col0 = lane * 16;
#pragma unroll
  for (int j = 0; j < 16; ++j)
    yv[j] = (yv[j] - mu) * rs * w1[col0 + j] + b1[col0 + j];
  short8 o0, o1;
#pragma unroll
  for (int j = 0; j < 8; ++j) { o0[j] = (short)f2bf(yv[j]); o1[j] = (short)f2bf(yv[8 + j]); }
  *(short8*)&X1[base] = o0;
  *(short8*)&X1[base + 8] = o1;

  if (lane < 4) {  // cols 0..63 feed the quantum FFN encoder
    short8 q0, q1;
#pragma unroll
    for (int j = 0; j < 16; ++j) {
      int c = col0 + j;
      float qv = cosf(yv[j] + fqp[c * 3]) * cosf(fqp[c * 3 + 1]);
      if (j < 8) q0[j] = (short)f2bf(qv); else q1[j - 8] = (short)f2bf(qv);
    }
    *(short8*)&Q[(size_t)row * 64 + col0] = q0;
    *(short8*)&Q[(size_t)row * 64 + col0 + 8] = q1;
  }
}

// ---------------- K4: ffn = Q @ Wf^T; out = LN2(x1 + ffn + fb) ------------
__global__ __launch_bounds__(256) void k_ffn(const u16* __restrict__ X1,
                                             const u16* __restrict__ Q,
                                             const u16* __restrict__ Wfb,
                                             const float* __restrict__ fb,
                                             const float* __restrict__ w2,
                                             const float* __restrict__ b2,
                                             float* __restrict__ out) {
  __shared__ float t2[16][1024];  // 64 KB
  int t = threadIdx.x, lane = t & 63, wv = t >> 6;
  int m0 = blockIdx.x * 16;
  int kof = (lane >> 4) * 8;
  const short8 a0v = *(const short8*)&Q[(size_t)(m0 + (lane & 15)) * 64 + kof];
  const short8 a1v = *(const short8*)&Q[(size_t)(m0 + (lane & 15)) * 64 + 32 + kof];
  int nbase = wv * 256;
#pragma unroll
  for (int ni = 0; ni < 16; ++ni) {
    int n = nbase + ni * 16 + (lane & 15);
    short8 b0 = *(const short8*)&Wfb[(size_t)n * 64 + kof];
    short8 b1 = *(const short8*)&Wfb[(size_t)n * 64 + 32 + kof];
    f32x4 acc = (f32x4){0.f, 0.f, 0.f, 0.f};
    acc = __builtin_amdgcn_mfma_f32_16x16x32_bf16(a0v, b0, acc, 0, 0, 0);
    acc = __builtin_amdgcn_mfma_f32_16x16x32_bf16(a1v, b1, acc, 0, 0, 0);
#pragma unroll
    for (int r = 0; r < 4; ++r) t2[(lane >> 4) * 4 + r][n] = acc[r];
  }
  __syncthreads();
  for (int rr = 0; rr < 4; ++rr) {
    int row = wv * 4 + rr;
    size_t grow = (size_t)(m0 + row) * 1024;
    float vv[16];
    float s = 0.f, s2 = 0.f;
#pragma unroll
    for (int j = 0; j < 16; ++j) {
      int col = j * 64 + lane;
      float val = bf2f(X1[grow + col]) + t2[row][col] + fb[col];
      vv[j] = val; s += val; s2 += val * val;
    }
#pragma unroll
    for (int m = 1; m < 64; m <<= 1) { s += __shfl_xor(s, m, 64); s2 += __shfl_xor(s2, m, 64); }
    float mu = s * (1.f / 1024.f);
    float var = s2 * (1.f / 1024.f) - mu * mu;
    float rs = rsqrtf(var + 1e-5f);
#pragma unroll
    for (int j = 0; j < 16; ++j) {
      int col = j * 64 + lane;
      out[grow + col] = (vv[j] - mu) * rs * w2[col] + b2[col];
    }
  }
}

extern "C" void kernel_launch(void* const* d_in, const int* in_sizes, int n_in,
                              void* d_out, int out_size, void* d_ws, size_t ws_size,
                              hipStream_t stream) {
  const float* x   = (const float*)d_in[0];
  const float* aqp = (const float*)d_in[1];
  const float* opw = (const float*)d_in[2];
  const float* opb = (const float*)d_in[3];
  const float* fqp = (const float*)d_in[4];
  const float* flw = (const float*)d_in[5];
  const float* flb = (const float*)d_in[6];
  const float* n1w = (const float*)d_in[7];
  const float* n1b = (const float*)d_in[8];
  const float* n2w = (const float*)d_in[9];
  const float* n2b = (const float*)d_in[10];
  float* out = (float*)d_out;

  char* ws = (char*)d_ws;
  u16* zbuf = (u16*)(ws + 0);          // Z (bf16), becomes X1 (overwritten by k_ln1)
  u16* Wb   = (u16*)(ws + 33554432);   // 1024x1024 bf16
  u16* Wfb  = (u16*)(ws + 35651584);   // 1024x64 bf16
  u16* Qb   = (u16*)(ws + 35782656);   // 16384x64 bf16

  // d_out doubles as pre-FFN scratch: bf16 Y in [0, 32MB). k_ffn fully
  // overwrites d_out with the final fp32 result afterwards.
  u16* Ybf = (u16*)d_out;

  k_conv<<<1088, 256, 0, stream>>>(opw, flw, Wb, Wfb);
  k_zenc<<<16384, 256, 0, stream>>>(x, aqp, zbuf);
  k_gemm<<<1024, 256, 0, stream>>>(zbuf, Wb, x, opb, Ybf);
  k_ln1<<<4096, 256, 0, stream>>>(Ybf, n1w, n1b, fqp, zbuf /*X1*/, Qb);
  k_ffn<<<1024, 256, 0, stream>>>(zbuf, Qb, Wfb, flb, n2w, n2b, out);
}

// Round 6
// 141.761 us; speedup vs baseline: 3.1745x; 1.0974x over previous
//
#include <hip/hip_runtime.h>
#include <math.h>

typedef __attribute__((ext_vector_type(8))) short short8;
typedef __attribute__((ext_vector_type(4))) float f32x4;
typedef unsigned short u16;

#define AS1 __attribute__((address_space(1)))
#define AS3 __attribute__((address_space(3)))
#define DEV static __device__ __forceinline__
#define MFMA_(a, b, c) __builtin_amdgcn_mfma_f32_16x16x32_bf16(a, b, c, 0, 0, 0)
#define BAR() __builtin_amdgcn_s_barrier()
#define LGKM0() asm volatile("s_waitcnt lgkmcnt(0)" ::: "memory")
#define VMC(n) asm volatile("s_waitcnt vmcnt(" #n ")" ::: "memory")
#define SETP(p) __builtin_amdgcn_s_setprio(p)

DEV u16 f2bf(float f) {
  union { float f; unsigned u; } v; v.f = f;
  unsigned r = v.u + 0x7FFFu + ((v.u >> 16) & 1u);
  return (u16)(r >> 16);
}
DEV float bf2f(u16 u) {
  union { unsigned u; float f; } v; v.u = ((unsigned)u) << 16;
  return v.f;
}

// ---------------- K0: convert weights to bf16 ----------------
__global__ __launch_bounds__(256) void k_conv(const float* __restrict__ W,
                                              const float* __restrict__ Wf,
                                              u16* __restrict__ Wb,
                                              u16* __restrict__ Wfb) {
  int i = (blockIdx.x * 256 + threadIdx.x) * 4;
  const int NW = 1024 * 1024;
  if (i < NW) {
    float4 v = *(const float4*)(W + i);
    ushort4 o = {f2bf(v.x), f2bf(v.y), f2bf(v.z), f2bf(v.w)};
    *(ushort4*)(Wb + i) = o;
  } else {
    int j = i - NW;  // < 65536
    float4 v = *(const float4*)(Wf + j);
    ushort4 o = {f2bf(v.x), f2bf(v.y), f2bf(v.z), f2bf(v.w)};
    *(ushort4*)(Wfb + j) = o;
  }
}

// ---------------- K1: z = cos(x + a0[d]) * cos(a1[d]), bf16 ----------------
__global__ __launch_bounds__(256) void k_zenc(const float* __restrict__ x,
                                              const float* __restrict__ qp, // [64][3]
                                              u16* __restrict__ z) {
  __shared__ float a0[64], c1[64];
  int t = threadIdx.x;
  if (t < 64) { a0[t] = qp[t * 3]; c1[t] = cosf(qp[t * 3 + 1]); }
  __syncthreads();
  size_t i = ((size_t)blockIdx.x * 256 + t) * 4;
  float4 xv = *(const float4*)(x + i);
  int d = (int)(i & 63);
  ushort4 o;
  o.x = f2bf(cosf(xv.x + a0[d + 0]) * c1[d + 0]);
  o.y = f2bf(cosf(xv.y + a0[d + 1]) * c1[d + 1]);
  o.z = f2bf(cosf(xv.z + a0[d + 2]) * c1[d + 2]);
  o.w = f2bf(cosf(xv.w + a0[d + 3]) * c1[d + 3]);
  *(ushort4*)(z + i) = o;
}

// ================= K2: 8-phase 256x256 GEMM (T3+T4+T5+T2) =================
// Y = Z @ W^T + x + b -> bf16. M=16384 N=1024 K=1024.
// 8 waves (2Mx4N), BK=64 as 2 k-halves; LDS = [2buf][2kh] 16KB units x (A,B).
// Per phase: ds_reads | stage 1 unit (2x global_load_lds w16) | bar |
// setprio(1) 16 MFMA setprio(0) | lgkm fence | vmcnt(10) even phases | bar.
// Units staged 2 tiles ahead into the region freed one phase earlier.
// Granule swizzle kg^=(r&3)^((r>>2)&3) applied on BOTH global-src and ds_read.
template <int P>
DEV void mm2(f32x4 (&acc)[8][4], const short8 (&av)[8], short8 b0, short8 b1) {
#pragma unroll
  for (int mi = 0; mi < 8; ++mi) {
    acc[mi][2 * P]     = MFMA_(av[mi], b0, acc[mi][2 * P]);
    acc[mi][2 * P + 1] = MFMA_(av[mi], b1, acc[mi][2 * P + 1]);
  }
}

__global__ __launch_bounds__(512, 2) void k_gemm(const u16* __restrict__ Z,
                                                 const u16* __restrict__ Wb,
                                                 const float* __restrict__ x,
                                                 const float* __restrict__ opb,
                                                 u16* __restrict__ Ybf) {
  __shared__ __attribute__((aligned(16))) u16 Alds[2][2][8192];  // 64 KB
  __shared__ __attribute__((aligned(16))) u16 Blds[2][2][8192];  // 64 KB
  const int bid = blockIdx.x;
  // XCD-chunked: xcd = bid&7 owns mt block of 8, all 4 nt (W chunk L2-shared)
  const int mt = (bid & 7) * 8 + ((bid >> 3) & 7);
  const int nt = bid >> 6;
  const int m0 = mt * 256, n0 = nt * 256;
  const int t = threadIdx.x, lane = t & 63, wv = t >> 6;
  const int wm = wv >> 2, wn = wv & 3;
  const int cl = lane & 15, kq = lane >> 4;

  // read-side swizzled bases (granule constant per lane)
  const int gsw = kq ^ (cl & 3) ^ ((cl >> 2) & 3);
  const int aoff = (wm * 128 + cl) * 32 + gsw * 8;
  const int boff = (wn * 64 + cl) * 32 + gsw * 8;

  // stage-side: thread owns LDS rows r0, r0+128; pre-swizzled global granule
  const int r0 = t >> 2;
  const int kgs = (t & 3) ^ (r0 & 3) ^ ((r0 >> 2) & 3);
  const size_t st0 = (size_t)r0 * 1024 + kgs * 8;
  const size_t st1 = st0 + (size_t)128 * 1024;
  const int d0 = wv * 512, d1 = 4096 + wv * 512;

  u16* const A00 = &Alds[0][0][0]; u16* const A01 = &Alds[0][1][0];
  u16* const A10 = &Alds[1][0][0]; u16* const A11 = &Alds[1][1][0];
  u16* const B00 = &Blds[0][0][0]; u16* const B01 = &Blds[0][1][0];
  u16* const B10 = &Blds[1][0][0]; u16* const B11 = &Blds[1][1][0];

  const u16* const zb = Z + (size_t)m0 * 1024;
  const u16* const wbp = Wb + (size_t)n0 * 1024;

  auto stage = [&](u16* unit, const u16* g0) {
    __builtin_amdgcn_global_load_lds((const AS1 unsigned int*)(g0 + st0),
                                     (AS3 unsigned int*)(unit + d0), 16, 0, 0);
    __builtin_amdgcn_global_load_lds((const AS1 unsigned int*)(g0 + st1),
                                     (AS3 unsigned int*)(unit + d1), 16, 0, 0);
  };

  f32x4 acc[8][4];
#pragma unroll
  for (int i = 0; i < 8; ++i)
#pragma unroll
    for (int j = 0; j < 4; ++j) acc[i][j] = (f32x4){0.f, 0.f, 0.f, 0.f};
  short8 av[8];

  auto rdA = [&](const u16* unit) {
#pragma unroll
    for (int mi = 0; mi < 8; ++mi)
      av[mi] = *(const short8*)&unit[aoff + mi * 512];
  };

  // ---- prologue: 7 units (tiles 0,1 minus B(1,h1)); keep 5 in flight ----
  stage(A00, zb);      stage(B00, wbp);
  stage(A01, zb + 32); stage(B01, wbp + 32);
  stage(A10, zb + 64); stage(B10, wbp + 64);
  stage(A11, zb + 96);
  VMC(10);
  BAR();

  short8 b0, b1;
#pragma unroll 1
  for (int I = 0; I < 7; ++I) {
    const u16* zt = zb + I * 128;   // tile u=2I k-base
    const u16* wt = wbp + I * 128;
    // P1: compute (u,h0,n01); stage B(u+1,h1)
    rdA(A00);
    b0 = *(const short8*)&B00[boff]; b1 = *(const short8*)&B00[boff + 512];
    stage(B11, wt + 96);
    BAR(); SETP(1); mm2<0>(acc, av, b0, b1); SETP(0); LGKM0(); BAR();
    // P2: (u,h0,n23); stage A(u+2,h0)
    b0 = *(const short8*)&B00[boff + 1024]; b1 = *(const short8*)&B00[boff + 1536];
    stage(A00, zt + 128);
    BAR(); SETP(1); mm2<1>(acc, av, b0, b1); SETP(0); LGKM0(); VMC(10); BAR();
    // P3: (u,h1,n01); stage B(u+2,h0)
    rdA(A01);
    b0 = *(const short8*)&B01[boff]; b1 = *(const short8*)&B01[boff + 512];
    stage(B00, wt + 128);
    BAR(); SETP(1); mm2<0>(acc, av, b0, b1); SETP(0); LGKM0(); BAR();
    // P4: (u,h1,n23); stage A(u+2,h1)
    b0 = *(const short8*)&B01[boff + 1024]; b1 = *(const short8*)&B01[boff + 1536];
    stage(A01, zt + 160);
    BAR(); SETP(1); mm2<1>(acc, av, b0, b1); SETP(0); LGKM0(); VMC(10); BAR();
    // P5: (u+1,h0,n01); stage B(u+2,h1)
    rdA(A10);
    b0 = *(const short8*)&B10[boff]; b1 = *(const short8*)&B10[boff + 512];
    stage(B01, wt + 160);
    BAR(); SETP(1); mm2<0>(acc, av, b0, b1); SETP(0); LGKM0(); BAR();
    // P6: (u+1,h0,n23); stage A(u+3,h0)
    b0 = *(const short8*)&B10[boff + 1024]; b1 = *(const short8*)&B10[boff + 1536];
    stage(A10, zt + 192);
    BAR(); SETP(1); mm2<1>(acc, av, b0, b1); SETP(0); LGKM0(); VMC(10); BAR();
    // P7: (u+1,h1,n01); stage B(u+3,h0)
    rdA(A11);
    b0 = *(const short8*)&B11[boff]; b1 = *(const short8*)&B11[boff + 512];
    stage(B10, wt + 192);
    BAR(); SETP(1); mm2<0>(acc, av, b0, b1); SETP(0); LGKM0(); BAR();
    // P8: (u+1,h1,n23); stage A(u+3,h1)
    b0 = *(const short8*)&B11[boff + 1024]; b1 = *(const short8*)&B11[boff + 1536];
    stage(A11, zt + 224);
    BAR(); SETP(1); mm2<1>(acc, av, b0, b1); SETP(0); LGKM0(); VMC(10); BAR();
  }

  // ---- epilogue iteration (tiles 14,15): only B(15,h1) left to stage ----
  {
    const u16* wt = wbp + 7 * 128;
    // P1
    rdA(A00);
    b0 = *(const short8*)&B00[boff]; b1 = *(const short8*)&B00[boff + 512];
    stage(B11, wt + 96);
    BAR(); SETP(1); mm2<0>(acc, av, b0, b1); SETP(0); LGKM0(); BAR();
    // P2
    b0 = *(const short8*)&B00[boff + 1024]; b1 = *(const short8*)&B00[boff + 1536];
    BAR(); SETP(1); mm2<1>(acc, av, b0, b1); SETP(0); LGKM0(); VMC(8); BAR();
    // P3
    rdA(A01);
    b0 = *(const short8*)&B01[boff]; b1 = *(const short8*)&B01[boff + 512];
    BAR(); SETP(1); mm2<0>(acc, av, b0, b1); SETP(0); LGKM0(); BAR();
    // P4
    b0 = *(const short8*)&B01[boff + 1024]; b1 = *(const short8*)&B01[boff + 1536];
    BAR(); SETP(1); mm2<1>(acc, av, b0, b1); SETP(0); LGKM0(); VMC(4); BAR();
    // P5
    rdA(A10);
    b0 = *(const short8*)&B10[boff]; b1 = *(const short8*)&B10[boff + 512];
    BAR(); SETP(1); mm2<0>(acc, av, b0, b1); SETP(0); LGKM0(); BAR();
    // P6
    b0 = *(const short8*)&B10[boff + 1024]; b1 = *(const short8*)&B10[boff + 1536];
    BAR(); SETP(1); mm2<1>(acc, av, b0, b1); SETP(0); LGKM0(); VMC(0); BAR();
    // P7
    rdA(A11);
    b0 = *(const short8*)&B11[boff]; b1 = *(const short8*)&B11[boff + 512];
    BAR(); SETP(1); mm2<0>(acc, av, b0, b1); SETP(0); LGKM0(); BAR();
    // P8
    b0 = *(const short8*)&B11[boff + 1024]; b1 = *(const short8*)&B11[boff + 1536];
    BAR(); SETP(1); mm2<1>(acc, av, b0, b1); SETP(0); LGKM0(); BAR();
  }

  // ---- C-write: v = acc + x + bias -> bf16 ----
  const int rb = m0 + wm * 128 + kq * 4;
  const int cb = n0 + wn * 64 + cl;
#pragma unroll
  for (int mi = 0; mi < 8; ++mi) {
#pragma unroll
    for (int ni = 0; ni < 4; ++ni) {
      int col = cb + ni * 16;
      float bcol = opb[col];
#pragma unroll
      for (int r = 0; r < 4; ++r) {
        size_t idx = (size_t)(rb + mi * 16 + r) * 1024 + col;
        Ybf[idx] = f2bf(acc[mi][ni][r] + x[idx] + bcol);
      }
    }
  }
}

// ---------------- K3: X1 = LN1(Ybf); Q = enc(X1[:, :64]) ------------------
__global__ __launch_bounds__(256) void k_ln1(const u16* __restrict__ Ybf,
                                             const float* __restrict__ w1,
                                             const float* __restrict__ b1,
                                             const float* __restrict__ fqp,
                                             u16* __restrict__ X1,
                                             u16* __restrict__ Q) {
  int t = threadIdx.x, lane = t & 63, wv = t >> 6;
  int row = blockIdx.x * 4 + wv;
  size_t base = (size_t)row * 1024 + lane * 16;
  short8 y0 = *(const short8*)&Ybf[base];
  short8 y1 = *(const short8*)&Ybf[base + 8];
  float yv[16];
#pragma unroll
  for (int j = 0; j < 8; ++j) yv[j] = bf2f((u16)y0[j]);
#pragma unroll
  for (int j = 0; j < 8; ++j) yv[8 + j] = bf2f((u16)y1[j]);
  float s = 0.f, s2 = 0.f;
#pragma unroll
  for (int j = 0; j < 16; ++j) { s += yv[j]; s2 += yv[j] * yv[j]; }
#pragma unroll
  for (int msk = 1; msk < 64; msk <<= 1) {
    s += __shfl_xor(s, msk, 64);
    s2 += __shfl_xor(s2, msk, 64);
  }
  float mu = s * (1.f / 1024.f);
  float var = s2 * (1.f / 1024.f) - mu * mu;
  float rs = rsqrtf(var + 1e-5f);

  int col0 = lane * 16;
#pragma unroll
  for (int j = 0; j < 16; ++j)
    yv[j] = (yv[j] - mu) * rs * w1[col0 + j] + b1[col0 + j];
  short8 o0, o1;
#pragma unroll
  for (int j = 0; j < 8; ++j) { o0[j] = (short)f2bf(yv[j]); o1[j] = (short)f2bf(yv[8 + j]); }
  *(short8*)&X1[base] = o0;
  *(short8*)&X1[base + 8] = o1;

  if (lane < 4) {  // cols 0..63 feed the quantum FFN encoder
    short8 q0, q1;
#pragma unroll
    for (int j = 0; j < 16; ++j) {
      int c = col0 + j;
      float qv = cosf(yv[j] + fqp[c * 3]) * cosf(fqp[c * 3 + 1]);
      if (j < 8) q0[j] = (short)f2bf(qv); else q1[j - 8] = (short)f2bf(qv);
    }
    *(short8*)&Q[(size_t)row * 64 + col0] = q0;
    *(short8*)&Q[(size_t)row * 64 + col0 + 8] = q1;
  }
}

// ---------------- K4: ffn = Q @ Wf^T; out = LN2(x1 + ffn + fb) ------------
__global__ __launch_bounds__(256) void k_ffn(const u16* __restrict__ X1,
                                             const u16* __restrict__ Q,
                                             const u16* __restrict__ Wfb,
                                             const float* __restrict__ fb,
                                             const float* __restrict__ w2,
                                             const float* __restrict__ b2,
                                             float* __restrict__ out) {
  __shared__ float t2[16][1024];  // 64 KB
  int t = threadIdx.x, lane = t & 63, wv = t >> 6;
  int m0 = blockIdx.x * 16;
  int kof = (lane >> 4) * 8;
  const short8 a0v = *(const short8*)&Q[(size_t)(m0 + (lane & 15)) * 64 + kof];
  const short8 a1v = *(const short8*)&Q[(size_t)(m0 + (lane & 15)) * 64 + 32 + kof];
  int nbase = wv * 256;
#pragma unroll
  for (int ni = 0; ni < 16; ++ni) {
    int n = nbase + ni * 16 + (lane & 15);
    short8 bb0 = *(const short8*)&Wfb[(size_t)n * 64 + kof];
    short8 bb1 = *(const short8*)&Wfb[(size_t)n * 64 + 32 + kof];
    f32x4 acc = (f32x4){0.f, 0.f, 0.f, 0.f};
    acc = MFMA_(a0v, bb0, acc);
    acc = MFMA_(a1v, bb1, acc);
#pragma unroll
    for (int r = 0; r < 4; ++r) t2[(lane >> 4) * 4 + r][n] = acc[r];
  }
  __syncthreads();
  for (int rr = 0; rr < 4; ++rr) {
    int row = wv * 4 + rr;
    size_t grow = (size_t)(m0 + row) * 1024;
    float vv[16];
    float s = 0.f, s2 = 0.f;
#pragma unroll
    for (int j = 0; j < 16; ++j) {
      int col = j * 64 + lane;
      float val = bf2f(X1[grow + col]) + t2[row][col] + fb[col];
      vv[j] = val; s += val; s2 += val * val;
    }
#pragma unroll
    for (int m = 1; m < 64; m <<= 1) { s += __shfl_xor(s, m, 64); s2 += __shfl_xor(s2, m, 64); }
    float mu = s * (1.f / 1024.f);
    float var = s2 * (1.f / 1024.f) - mu * mu;
    float rs = rsqrtf(var + 1e-5f);
#pragma unroll
    for (int j = 0; j < 16; ++j) {
      int col = j * 64 + lane;
      out[grow + col] = (vv[j] - mu) * rs * w2[col] + b2[col];
    }
  }
}

extern "C" void kernel_launch(void* const* d_in, const int* in_sizes, int n_in,
                              void* d_out, int out_size, void* d_ws, size_t ws_size,
                              hipStream_t stream) {
  const float* x   = (const float*)d_in[0];
  const float* aqp = (const float*)d_in[1];
  const float* opw = (const float*)d_in[2];
  const float* opb = (const float*)d_in[3];
  const float* fqp = (const float*)d_in[4];
  const float* flw = (const float*)d_in[5];
  const float* flb = (const float*)d_in[6];
  const float* n1w = (const float*)d_in[7];
  const float* n1b = (const float*)d_in[8];
  const float* n2w = (const float*)d_in[9];
  const float* n2b = (const float*)d_in[10];
  float* out = (float*)d_out;

  char* ws = (char*)d_ws;
  u16* zbuf = (u16*)(ws + 0);          // Z (bf16), becomes X1 (overwritten by k_ln1)
  u16* Wb   = (u16*)(ws + 33554432);   // 1024x1024 bf16
  u16* Wfb  = (u16*)(ws + 35651584);   // 1024x64 bf16
  u16* Qb   = (u16*)(ws + 35782656);   // 16384x64 bf16

  // d_out doubles as pre-FFN scratch: bf16 Y in [0, 32MB). k_ffn fully
  // overwrites d_out with the final fp32 result afterwards.
  u16* Ybf = (u16*)d_out;

  k_conv<<<1088, 256, 0, stream>>>(opw, flw, Wb, Wfb);
  k_zenc<<<16384, 256, 0, stream>>>(x, aqp, zbuf);
  k_gemm<<<256, 512, 0, stream>>>(zbuf, Wb, x, opb, Ybf);
  k_ln1<<<4096, 256, 0, stream>>>(Ybf, n1w, n1b, fqp, zbuf /*X1*/, Qb);
  k_ffn<<<1024, 256, 0, stream>>>(zbuf, Qb, Wfb, flb, n2w, n2b, out);
}

// Round 7
// 139.354 us; speedup vs baseline: 3.2293x; 1.0173x over previous
//
#include <hip/hip_runtime.h>
#include <math.h>

typedef __attribute__((ext_vector_type(8))) short short8;
typedef __attribute__((ext_vector_type(4))) float f32x4;
typedef unsigned short u16;

#define AS1 __attribute__((address_space(1)))
#define AS3 __attribute__((address_space(3)))
#define DEV static __device__ __forceinline__
#define MFMA_(a, b, c) __builtin_amdgcn_mfma_f32_16x16x32_bf16(a, b, c, 0, 0, 0)
#define BAR() __builtin_amdgcn_s_barrier()
#define LGKM0() asm volatile("s_waitcnt lgkmcnt(0)" ::: "memory")
#define VMC(n) asm volatile("s_waitcnt vmcnt(" #n ")" ::: "memory")
#define SETP(p) __builtin_amdgcn_s_setprio(p)

DEV u16 f2bf(float f) {
  union { float f; unsigned u; } v; v.f = f;
  unsigned r = v.u + 0x7FFFu + ((v.u >> 16) & 1u);
  return (u16)(r >> 16);
}
DEV float bf2f(u16 u) {
  union { unsigned u; float f; } v; v.u = ((unsigned)u) << 16;
  return v.f;
}

// ---------------- K0: convert weights to bf16 ----------------
__global__ __launch_bounds__(256) void k_conv(const float* __restrict__ W,
                                              const float* __restrict__ Wf,
                                              u16* __restrict__ Wb,
                                              u16* __restrict__ Wfb) {
  int i = (blockIdx.x * 256 + threadIdx.x) * 4;
  const int NW = 1024 * 1024;
  if (i < NW) {
    float4 v = *(const float4*)(W + i);
    ushort4 o = {f2bf(v.x), f2bf(v.y), f2bf(v.z), f2bf(v.w)};
    *(ushort4*)(Wb + i) = o;
  } else {
    int j = i - NW;  // < 65536
    float4 v = *(const float4*)(Wf + j);
    ushort4 o = {f2bf(v.x), f2bf(v.y), f2bf(v.z), f2bf(v.w)};
    *(ushort4*)(Wfb + j) = o;
  }
}

// ---------------- K1: z = cos(x + a0[d]) * cos(a1[d]), bf16 ----------------
__global__ __launch_bounds__(256) void k_zenc(const float* __restrict__ x,
                                              const float* __restrict__ qp, // [64][3]
                                              u16* __restrict__ z) {
  __shared__ float a0[64], c1[64];
  int t = threadIdx.x;
  if (t < 64) { a0[t] = qp[t * 3]; c1[t] = cosf(qp[t * 3 + 1]); }
  __syncthreads();
  size_t i = ((size_t)blockIdx.x * 256 + t) * 4;
  float4 xv = *(const float4*)(x + i);
  int d = (int)(i & 63);
  ushort4 o;
  o.x = f2bf(cosf(xv.x + a0[d + 0]) * c1[d + 0]);
  o.y = f2bf(cosf(xv.y + a0[d + 1]) * c1[d + 1]);
  o.z = f2bf(cosf(xv.z + a0[d + 2]) * c1[d + 2]);
  o.w = f2bf(cosf(xv.w + a0[d + 3]) * c1[d + 3]);
  *(ushort4*)(z + i) = o;
}

// ================= K2: 8-phase 256x256 GEMM (T3+T4+T5+T2) =================
// Y = Z @ W^T + x + b -> bf16. M=16384 N=1024 K=1024.
// 8 waves (2Mx4N), BK=64 as 2 k-halves; LDS = [2buf][2kh] 16KB units x (A,B).
// Swizzle = round-5's measured-zero-conflict function (r6's variant cost
// exactly +4 cy per ds_read_b128 -> LDS became the critical path):
//   read granule  gsw = kq ^ ((cl>>1)&3)   [rows == cl mod 8-periods]
//   stage granule kgs = (t&3) ^ ((t>>3)&3) [= (row>>1)&3, rows r0 & r0+128]
template <int P>
DEV void mm2(f32x4 (&acc)[8][4], const short8 (&av)[8], short8 b0, short8 b1) {
#pragma unroll
  for (int mi = 0; mi < 8; ++mi) {
    acc[mi][2 * P]     = MFMA_(av[mi], b0, acc[mi][2 * P]);
    acc[mi][2 * P + 1] = MFMA_(av[mi], b1, acc[mi][2 * P + 1]);
  }
}

__global__ __launch_bounds__(512, 2) void k_gemm(const u16* __restrict__ Z,
                                                 const u16* __restrict__ Wb,
                                                 const float* __restrict__ x,
                                                 const float* __restrict__ opb,
                                                 u16* __restrict__ Ybf) {
  __shared__ __attribute__((aligned(16))) u16 Alds[2][2][8192];  // 64 KB
  __shared__ __attribute__((aligned(16))) u16 Blds[2][2][8192];  // 64 KB
  const int bid = blockIdx.x;
  // XCD-chunked: xcd = bid&7 owns mt block of 8, all 4 nt (W chunk L2-shared)
  const int mt = (bid & 7) * 8 + ((bid >> 3) & 7);
  const int nt = bid >> 6;
  const int m0 = mt * 256, n0 = nt * 256;
  const int t = threadIdx.x, lane = t & 63, wv = t >> 6;
  const int wm = wv >> 2, wn = wv & 3;
  const int cl = lane & 15, kq = lane >> 4;

  // read-side swizzled bases (round-5 function; row bases are mult. of 8)
  const int gsw = kq ^ ((cl >> 1) & 3);
  const int aoff = (wm * 128 + cl) * 32 + gsw * 8;
  const int boff = (wn * 64 + cl) * 32 + gsw * 8;

  // stage-side: thread owns LDS rows r0, r0+128; pre-swizzled global granule
  const int r0 = t >> 2;
  const int kgs = (t & 3) ^ ((t >> 3) & 3);
  const size_t st0 = (size_t)r0 * 1024 + kgs * 8;
  const size_t st1 = st0 + (size_t)128 * 1024;
  const int d0 = wv * 512, d1 = 4096 + wv * 512;

  u16* const A00 = &Alds[0][0][0]; u16* const A01 = &Alds[0][1][0];
  u16* const A10 = &Alds[1][0][0]; u16* const A11 = &Alds[1][1][0];
  u16* const B00 = &Blds[0][0][0]; u16* const B01 = &Blds[0][1][0];
  u16* const B10 = &Blds[1][0][0]; u16* const B11 = &Blds[1][1][0];

  const u16* const zb = Z + (size_t)m0 * 1024;
  const u16* const wbp = Wb + (size_t)n0 * 1024;

  auto stage = [&](u16* unit, const u16* g0) {
    __builtin_amdgcn_global_load_lds((const AS1 unsigned int*)(g0 + st0),
                                     (AS3 unsigned int*)(unit + d0), 16, 0, 0);
    __builtin_amdgcn_global_load_lds((const AS1 unsigned int*)(g0 + st1),
                                     (AS3 unsigned int*)(unit + d1), 16, 0, 0);
  };

  f32x4 acc[8][4];
#pragma unroll
  for (int i = 0; i < 8; ++i)
#pragma unroll
    for (int j = 0; j < 4; ++j) acc[i][j] = (f32x4){0.f, 0.f, 0.f, 0.f};
  short8 av[8];

  auto rdA = [&](const u16* unit) {
#pragma unroll
    for (int mi = 0; mi < 8; ++mi)
      av[mi] = *(const short8*)&unit[aoff + mi * 512];
  };

  // ---- prologue: 7 units (tiles 0,1 minus B(1,h1)); keep 5 in flight ----
  stage(A00, zb);      stage(B00, wbp);
  stage(A01, zb + 32); stage(B01, wbp + 32);
  stage(A10, zb + 64); stage(B10, wbp + 64);
  stage(A11, zb + 96);
  VMC(10);
  BAR();

  short8 b0, b1;
#pragma unroll 1
  for (int I = 0; I < 7; ++I) {
    const u16* zt = zb + I * 128;   // tile u=2I k-base
    const u16* wt = wbp + I * 128;
    // P1: compute (u,h0,n01); stage B(u+1,h1)
    rdA(A00);
    b0 = *(const short8*)&B00[boff]; b1 = *(const short8*)&B00[boff + 512];
    stage(B11, wt + 96);
    BAR(); SETP(1); mm2<0>(acc, av, b0, b1); SETP(0); LGKM0(); BAR();
    // P2: (u,h0,n23); stage A(u+2,h0)
    b0 = *(const short8*)&B00[boff + 1024]; b1 = *(const short8*)&B00[boff + 1536];
    stage(A00, zt + 128);
    BAR(); SETP(1); mm2<1>(acc, av, b0, b1); SETP(0); LGKM0(); VMC(10); BAR();
    // P3: (u,h1,n01); stage B(u+2,h0)
    rdA(A01);
    b0 = *(const short8*)&B01[boff]; b1 = *(const short8*)&B01[boff + 512];
    stage(B00, wt + 128);
    BAR(); SETP(1); mm2<0>(acc, av, b0, b1); SETP(0); LGKM0(); BAR();
    // P4: (u,h1,n23); stage A(u+2,h1)
    b0 = *(const short8*)&B01[boff + 1024]; b1 = *(const short8*)&B01[boff + 1536];
    stage(A01, zt + 160);
    BAR(); SETP(1); mm2<1>(acc, av, b0, b1); SETP(0); LGKM0(); VMC(10); BAR();
    // P5: (u+1,h0,n01); stage B(u+2,h1)
    rdA(A10);
    b0 = *(const short8*)&B10[boff]; b1 = *(const short8*)&B10[boff + 512];
    stage(B01, wt + 160);
    BAR(); SETP(1); mm2<0>(acc, av, b0, b1); SETP(0); LGKM0(); BAR();
    // P6: (u+1,h0,n23); stage A(u+3,h0)
    b0 = *(const short8*)&B10[boff + 1024]; b1 = *(const short8*)&B10[boff + 1536];
    stage(A10, zt + 192);
    BAR(); SETP(1); mm2<1>(acc, av, b0, b1); SETP(0); LGKM0(); VMC(10); BAR();
    // P7: (u+1,h1,n01); stage B(u+3,h0)
    rdA(A11);
    b0 = *(const short8*)&B11[boff]; b1 = *(const short8*)&B11[boff + 512];
    stage(B10, wt + 192);
    BAR(); SETP(1); mm2<0>(acc, av, b0, b1); SETP(0); LGKM0(); BAR();
    // P8: (u+1,h1,n23); stage A(u+3,h1)
    b0 = *(const short8*)&B11[boff + 1024]; b1 = *(const short8*)&B11[boff + 1536];
    stage(A11, zt + 224);
    BAR(); SETP(1); mm2<1>(acc, av, b0, b1); SETP(0); LGKM0(); VMC(10); BAR();
  }

  // ---- epilogue iteration (tiles 14,15): only B(15,h1) left to stage ----
  {
    const u16* wt = wbp + 7 * 128;
    // P1
    rdA(A00);
    b0 = *(const short8*)&B00[boff]; b1 = *(const short8*)&B00[boff + 512];
    stage(B11, wt + 96);
    BAR(); SETP(1); mm2<0>(acc, av, b0, b1); SETP(0); LGKM0(); BAR();
    // P2
    b0 = *(const short8*)&B00[boff + 1024]; b1 = *(const short8*)&B00[boff + 1536];
    BAR(); SETP(1); mm2<1>(acc, av, b0, b1); SETP(0); LGKM0(); VMC(8); BAR();
    // P3
    rdA(A01);
    b0 = *(const short8*)&B01[boff]; b1 = *(const short8*)&B01[boff + 512];
    BAR(); SETP(1); mm2<0>(acc, av, b0, b1); SETP(0); LGKM0(); BAR();
    // P4
    b0 = *(const short8*)&B01[boff + 1024]; b1 = *(const short8*)&B01[boff + 1536];
    BAR(); SETP(1); mm2<1>(acc, av, b0, b1); SETP(0); LGKM0(); VMC(4); BAR();
    // P5
    rdA(A10);
    b0 = *(const short8*)&B10[boff]; b1 = *(const short8*)&B10[boff + 512];
    BAR(); SETP(1); mm2<0>(acc, av, b0, b1); SETP(0); LGKM0(); BAR();
    // P6
    b0 = *(const short8*)&B10[boff + 1024]; b1 = *(const short8*)&B10[boff + 1536];
    BAR(); SETP(1); mm2<1>(acc, av, b0, b1); SETP(0); LGKM0(); VMC(0); BAR();
    // P7
    rdA(A11);
    b0 = *(const short8*)&B11[boff]; b1 = *(const short8*)&B11[boff + 512];
    BAR(); SETP(1); mm2<0>(acc, av, b0, b1); SETP(0); LGKM0(); BAR();
    // P8
    b0 = *(const short8*)&B11[boff + 1024]; b1 = *(const short8*)&B11[boff + 1536];
    BAR(); SETP(1); mm2<1>(acc, av, b0, b1); SETP(0); LGKM0(); BAR();
  }

  // ---- C-write: v = acc + x + bias -> bf16 ----
  const int rb = m0 + wm * 128 + kq * 4;
  const int cb = n0 + wn * 64 + cl;
#pragma unroll
  for (int mi = 0; mi < 8; ++mi) {
#pragma unroll
    for (int ni = 0; ni < 4; ++ni) {
      int col = cb + ni * 16;
      float bcol = opb[col];
#pragma unroll
      for (int r = 0; r < 4; ++r) {
        size_t idx = (size_t)(rb + mi * 16 + r) * 1024 + col;
        Ybf[idx] = f2bf(acc[mi][ni][r] + x[idx] + bcol);
      }
    }
  }
}

// ---------------- K3: X1 = LN1(Ybf); Q = enc(X1[:, :64]) ------------------
__global__ __launch_bounds__(256) void k_ln1(const u16* __restrict__ Ybf,
                                             const float* __restrict__ w1,
                                             const float* __restrict__ b1,
                                             const float* __restrict__ fqp,
                                             u16* __restrict__ X1,
                                             u16* __restrict__ Q) {
  int t = threadIdx.x, lane = t & 63, wv = t >> 6;
  int row = blockIdx.x * 4 + wv;
  size_t base = (size_t)row * 1024 + lane * 16;
  short8 y0 = *(const short8*)&Ybf[base];
  short8 y1 = *(const short8*)&Ybf[base + 8];
  float yv[16];
#pragma unroll
  for (int j = 0; j < 8; ++j) yv[j] = bf2f((u16)y0[j]);
#pragma unroll
  for (int j = 0; j < 8; ++j) yv[8 + j] = bf2f((u16)y1[j]);
  float s = 0.f, s2 = 0.f;
#pragma unroll
  for (int j = 0; j < 16; ++j) { s += yv[j]; s2 += yv[j] * yv[j]; }
#pragma unroll
  for (int msk = 1; msk < 64; msk <<= 1) {
    s += __shfl_xor(s, msk, 64);
    s2 += __shfl_xor(s2, msk, 64);
  }
  float mu = s * (1.f / 1024.f);
  float var = s2 * (1.f / 1024.f) - mu * mu;
  float rs = rsqrtf(var + 1e-5f);

  int col0 = lane * 16;
#pragma unroll
  for (int j = 0; j < 16; ++j)
    yv[j] = (yv[j] - mu) * rs * w1[col0 + j] + b1[col0 + j];
  short8 o0, o1;
#pragma unroll
  for (int j = 0; j < 8; ++j) { o0[j] = (short)f2bf(yv[j]); o1[j] = (short)f2bf(yv[8 + j]); }
  *(short8*)&X1[base] = o0;
  *(short8*)&X1[base + 8] = o1;

  if (lane < 4) {  // cols 0..63 feed the quantum FFN encoder
    short8 q0, q1;
#pragma unroll
    for (int j = 0; j < 16; ++j) {
      int c = col0 + j;
      float qv = cosf(yv[j] + fqp[c * 3]) * cosf(fqp[c * 3 + 1]);
      if (j < 8) q0[j] = (short)f2bf(qv); else q1[j - 8] = (short)f2bf(qv);
    }
    *(short8*)&Q[(size_t)row * 64 + col0] = q0;
    *(short8*)&Q[(size_t)row * 64 + col0 + 8] = q1;
  }
}

// ---------------- K4: ffn = Q @ Wf^T; out = LN2(x1 + ffn + fb) ------------
__global__ __launch_bounds__(256) void k_ffn(const u16* __restrict__ X1,
                                             const u16* __restrict__ Q,
                                             const u16* __restrict__ Wfb,
                                             const float* __restrict__ fb,
                                             const float* __restrict__ w2,
                                             const float* __restrict__ b2,
                                             float* __restrict__ out) {
  __shared__ float t2[16][1024];  // 64 KB
  int t = threadIdx.x, lane = t & 63, wv = t >> 6;
  int m0 = blockIdx.x * 16;
  int kof = (lane >> 4) * 8;
  const short8 a0v = *(const short8*)&Q[(size_t)(m0 + (lane & 15)) * 64 + kof];
  const short8 a1v = *(const short8*)&Q[(size_t)(m0 + (lane & 15)) * 64 + 32 + kof];
  int nbase = wv * 256;
#pragma unroll
  for (int ni = 0; ni < 16; ++ni) {
    int n = nbase + ni * 16 + (lane & 15);
    short8 bb0 = *(const short8*)&Wfb[(size_t)n * 64 + kof];
    short8 bb1 = *(const short8*)&Wfb[(size_t)n * 64 + 32 + kof];
    f32x4 acc = (f32x4){0.f, 0.f, 0.f, 0.f};
    acc = MFMA_(a0v, bb0, acc);
    acc = MFMA_(a1v, bb1, acc);
#pragma unroll
    for (int r = 0; r < 4; ++r) t2[(lane >> 4) * 4 + r][n] = acc[r];
  }
  __syncthreads();
  for (int rr = 0; rr < 4; ++rr) {
    int row = wv * 4 + rr;
    size_t grow = (size_t)(m0 + row) * 1024;
    float vv[16];
    float s = 0.f, s2 = 0.f;
#pragma unroll
    for (int j = 0; j < 16; ++j) {
      int col = j * 64 + lane;
      float val = bf2f(X1[grow + col]) + t2[row][col] + fb[col];
      vv[j] = val; s += val; s2 += val * val;
    }
#pragma unroll
    for (int m = 1; m < 64; m <<= 1) { s += __shfl_xor(s, m, 64); s2 += __shfl_xor(s2, m, 64); }
    float mu = s * (1.f / 1024.f);
    float var = s2 * (1.f / 1024.f) - mu * mu;
    float rs = rsqrtf(var + 1e-5f);
#pragma unroll
    for (int j = 0; j < 16; ++j) {
      int col = j * 64 + lane;
      out[grow + col] = (vv[j] - mu) * rs * w2[col] + b2[col];
    }
  }
}

extern "C" void kernel_launch(void* const* d_in, const int* in_sizes, int n_in,
                              void* d_out, int out_size, void* d_ws, size_t ws_size,
                              hipStream_t stream) {
  const float* x   = (const float*)d_in[0];
  const float* aqp = (const float*)d_in[1];
  const float* opw = (const float*)d_in[2];
  const float* opb = (const float*)d_in[3];
  const float* fqp = (const float*)d_in[4];
  const float* flw = (const float*)d_in[5];
  const float* flb = (const float*)d_in[6];
  const float* n1w = (const float*)d_in[7];
  const float* n1b = (const float*)d_in[8];
  const float* n2w = (const float*)d_in[9];
  const float* n2b = (const float*)d_in[10];
  float* out = (float*)d_out;

  char* ws = (char*)d_ws;
  u16* zbuf = (u16*)(ws + 0);          // Z (bf16), becomes X1 (overwritten by k_ln1)
  u16* Wb   = (u16*)(ws + 33554432);   // 1024x1024 bf16
  u16* Wfb  = (u16*)(ws + 35651584);   // 1024x64 bf16
  u16* Qb   = (u16*)(ws + 35782656);   // 16384x64 bf16

  // d_out doubles as pre-FFN scratch: bf16 Y in [0, 32MB). k_ffn fully
  // overwrites d_out with the final fp32 result afterwards.
  u16* Ybf = (u16*)d_out;

  k_conv<<<1088, 256, 0, stream>>>(opw, flw, Wb, Wfb);
  k_zenc<<<16384, 256, 0, stream>>>(x, aqp, zbuf);
  k_gemm<<<256, 512, 0, stream>>>(zbuf, Wb, x, opb, Ybf);
  k_ln1<<<4096, 256, 0, stream>>>(Ybf, n1w, n1b, fqp, zbuf /*X1*/, Qb);
  k_ffn<<<1024, 256, 0, stream>>>(zbuf, Qb, Wfb, flb, n2w, n2b, out);
}